// Round 1
// baseline (21.494 us; speedup 1.0000x reference)
//
#include <hip/hip_runtime.h>

// LIF neuron Euler integration, T = 3.5M steps, scalar input current.
//
// Key structural insight: on every spike, v is reset to EXACTLY
// V_RESET = 0.0f, which equals the initial state. The fp32 dynamics are
// therefore exactly periodic: spikes[t] = (t > 0 && t % P == 0), where P is
// the number of fp32 Euler steps from v = 0 to the first v_new >= 1.0f.
// For I = 1.5, alpha = 0.005: P = 220 (crossing margins ~4e-4 / ~2e-3, far
// above any fp32 rounding ambiguity).
//
// Kernel A: single thread replicates the reference's fp32 arithmetic
//           bit-exactly (no FMA contraction, same op order, alpha computed
//           as float(double(1e-4)/double(0.02)) to match jnp.float32(DT/TAU))
//           and writes P to workspace. Caps at T-1 steps: if no spike occurs
//           within the scan length the output is all zeros, matching the ref.
// Kernel B: parallel fill of the 3.5M-element fp32 spike train, float4
//           stores, one integer division per thread (4 elems/thread).

__global__ void lif_period_kernel(const float* __restrict__ input_current,
                                  unsigned* __restrict__ p_out,
                                  int n_steps) {
#pragma clang fp contract(off)
    const float I = input_current[0];
    const float alpha = (float)(1e-4 / 0.02);  // == jnp.float32(DT / TAU)
    unsigned P = 0;
    float v = 0.0f;
    for (int n = 1; n < n_steps; ++n) {
        float d = (I - v) * alpha;      // (-v + I) * alpha, identical in IEEE
        float v_new = v + d;
        if (v_new >= 1.0f) { P = (unsigned)n; break; }
        if (v_new == v) break;          // converged below threshold: no spike ever
        v = v_new;
    }
    p_out[0] = P;
}

__global__ void lif_fill_kernel(float* __restrict__ out, int n,
                                const unsigned* __restrict__ p_in) {
    const unsigned P = p_in[0];   // uniform broadcast load
    const int i0 = (int)((blockIdx.x * blockDim.x + threadIdx.x) * 4u);
    if (i0 >= n) return;

    float vals[4] = {0.0f, 0.0f, 0.0f, 0.0f};
    if (P != 0u) {
        unsigned r = (unsigned)i0 % P;  // one division per thread
#pragma unroll
        for (int j = 0; j < 4; ++j) {
            vals[j] = (r == 0u && (i0 + j) != 0) ? 1.0f : 0.0f;
            if (++r == P) r = 0u;
        }
    }

    if (i0 + 4 <= n) {
        *reinterpret_cast<float4*>(out + i0) =
            make_float4(vals[0], vals[1], vals[2], vals[3]);
    } else {
        for (int j = 0; j < 4 && (i0 + j) < n; ++j) out[i0 + j] = vals[j];
    }
}

extern "C" void kernel_launch(void* const* d_in, const int* in_sizes, int n_in,
                              void* d_out, int out_size, void* d_ws, size_t ws_size,
                              hipStream_t stream) {
    const float* d_I = (const float*)d_in[0];   // input_current (scalar)
    float* out = (float*)d_out;                 // T fp32 spikes
    unsigned* pbuf = (unsigned*)d_ws;           // P lives in workspace

    lif_period_kernel<<<1, 1, 0, stream>>>(d_I, pbuf, out_size);

    const int nthreads = (out_size + 3) / 4;
    const int nblocks  = (nthreads + 255) / 256;
    lif_fill_kernel<<<nblocks, 256, 0, stream>>>(out, out_size, pbuf);
}

// Round 2
// 20.932 us; speedup vs baseline: 1.0268x; 1.0268x over previous
//
#include <hip/hip_runtime.h>

// LIF neuron Euler integration, T = 3.5M steps, scalar input current.
//
// Structural insight (verified R1, absmax = 0): spike resets v to exactly
// V_RESET = 0.0f == initial state, so the fp32 dynamics are exactly periodic:
// spikes[t] = (t > 0 && t % P == 0), where P = number of fp32 Euler steps
// from v=0 to the first v_new >= 1.0f (P = 220 for I = 1.5).
//
// R2 change: fuse period-compute + fill into ONE kernel (R1's two serially
// dependent dispatches cost ~18 us of launch/drain overhead vs ~3.5 us of
// actual work). Thread 0 of each block replicates the reference fp32
// arithmetic bit-exactly (fp contract off, same op order, alpha =
// float(double(1e-4)/double(0.02)) matching jnp.float32(DT/TAU)), broadcasts
// P via LDS, then all threads grid-stride fill with float4 stores.

__global__ void lif_fused_kernel(const float* __restrict__ input_current,
                                 float* __restrict__ out, int n) {
    __shared__ unsigned sP;
    if (threadIdx.x == 0) {
#pragma clang fp contract(off)
        const float I = input_current[0];
        const float alpha = (float)(1e-4 / 0.02);  // == jnp.float32(DT / TAU)
        unsigned P = 0;
        float v = 0.0f;
        for (int t = 1; t < n; ++t) {
            float v_new = v + (I - v) * alpha;   // == v + (-v + I)*alpha in IEEE
            if (v_new >= 1.0f) { P = (unsigned)t; break; }
            if (v_new == v) break;               // converged below threshold
            v = v_new;
        }
        sP = P;
    }
    __syncthreads();
    const unsigned P = sP;
    const unsigned un = (unsigned)n;

    const unsigned tid    = blockIdx.x * blockDim.x + threadIdx.x;
    const unsigned stride = gridDim.x * blockDim.x * 4u;
    unsigned i0 = tid * 4u;

    if (P == 0u) {  // no spike ever: all zeros
        const float4 z = make_float4(0.f, 0.f, 0.f, 0.f);
        for (; i0 + 4u <= un; i0 += stride)
            *reinterpret_cast<float4*>(out + i0) = z;
        for (; i0 < un; ++i0) out[i0] = 0.0f;
        return;
    }

    unsigned r    = i0 % P;        // one integer division per thread
    unsigned smod = stride % P;    // cheap add-with-wrap thereafter
    for (; i0 + 4u <= un; i0 += stride) {
        float4 vals;
        unsigned rr = r;
        vals.x = (rr == 0u && i0 != 0u) ? 1.0f : 0.0f;
        rr = (rr + 1u == P) ? 0u : rr + 1u;
        vals.y = (rr == 0u) ? 1.0f : 0.0f;
        rr = (rr + 1u == P) ? 0u : rr + 1u;
        vals.z = (rr == 0u) ? 1.0f : 0.0f;
        rr = (rr + 1u == P) ? 0u : rr + 1u;
        vals.w = (rr == 0u) ? 1.0f : 0.0f;
        *reinterpret_cast<float4*>(out + i0) = vals;
        r += smod;
        if (r >= P) r -= P;
    }
    for (; i0 < un; ++i0)
        out[i0] = ((i0 % P) == 0u && i0 != 0u) ? 1.0f : 0.0f;
}

extern "C" void kernel_launch(void* const* d_in, const int* in_sizes, int n_in,
                              void* d_out, int out_size, void* d_ws, size_t ws_size,
                              hipStream_t stream) {
    const float* d_I = (const float*)d_in[0];   // input_current (scalar)
    float* out = (float*)d_out;                 // T fp32 spikes

    lif_fused_kernel<<<512, 256, 0, stream>>>(d_I, out, out_size);
}

// Round 3
// 18.909 us; speedup vs baseline: 1.1367x; 1.1070x over previous
//
#include <hip/hip_runtime.h>

// LIF neuron Euler integration, T = 3.5M steps, scalar input current.
//
// Structural insight (verified R1/R2, absmax = 0): every spike resets v to
// exactly V_RESET = 0.0f == the initial state, so the fp32 dynamics are
// exactly periodic: spikes[t] = (t > 0 && t % P == 0), P = number of fp32
// Euler steps from v=0 to first v_new >= 1.0f (P = 220 for I = 1.5).
//
// R3 change: overlap the serial P-loop with the fill. Zeros (99.97% of the
// output) don't depend on P. Per block (256 thr = 4 waves, contiguous span):
//   wave 0, lane 0 : bit-exact fp32 P-loop (contract off, ref op order,
//                    alpha = float(double(1e-4)/double(0.02)))
//   waves 1..3     : zero-fill the block's span with float4 stores (starts
//                    immediately, no P dependency)
//   __syncthreads(); wave 0 patches out[t]=1.0f at multiples of P inside
//   the block's own span (~31 positions; same-block => no race).
// Critical path becomes max(P-loop ~1.5us, fill ~2us) instead of their sum.

__global__ void lif_fused_kernel(const float* __restrict__ input_current,
                                 float* __restrict__ out, int n, int span) {
    __shared__ unsigned sP;

    const unsigned un  = (unsigned)n;
    const unsigned lo  = (unsigned)blockIdx.x * (unsigned)span;
    if (lo >= un) return;
    unsigned hi = lo + (unsigned)span;
    if (hi > un) hi = un;

    const int wave = threadIdx.x >> 6;
    const int lane = threadIdx.x & 63;

    if (wave == 0) {
        if (lane == 0) {
#pragma clang fp contract(off)
            const float I = input_current[0];
            const float alpha = (float)(1e-4 / 0.02);  // == jnp.float32(DT/TAU)
            unsigned P = 0;
            float v = 0.0f;
            for (int t = 1; t < n; ++t) {
                float v_new = v + (I - v) * alpha;  // == v + (-v + I)*alpha
                if (v_new >= 1.0f) { P = (unsigned)t; break; }
                if (v_new == v) break;              // converged below threshold
                v = v_new;
            }
            sP = P;
        }
    } else {
        // 192 threads zero-fill [lo, hi) with float4 stores
        const unsigned t2     = (unsigned)(threadIdx.x - 64);
        const unsigned nf4    = (hi - lo) >> 2;          // lo, span are x4-aligned
        const float4   z      = make_float4(0.f, 0.f, 0.f, 0.f);
        for (unsigned f = t2; f < nf4; f += 192u)
            *reinterpret_cast<float4*>(out + lo + (f << 2)) = z;
        // scalar tail (only possible in the last block if n % 4 != 0)
        for (unsigned i = lo + (nf4 << 2) + t2; i < hi; i += 192u)
            out[i] = 0.0f;
    }

    __syncthreads();

    if (wave == 0) {
        const unsigned P = sP;
        if (P != 0u) {
            unsigned first = ((lo + P - 1u) / P) * P;   // first multiple of P >= lo
            if (first == 0u) first = P;                 // t = 0 is never a spike
            for (unsigned t = first + (unsigned)lane * P; t < hi; t += 64u * P)
                out[t] = 1.0f;
        }
    }
}

extern "C" void kernel_launch(void* const* d_in, const int* in_sizes, int n_in,
                              void* d_out, int out_size, void* d_ws, size_t ws_size,
                              hipStream_t stream) {
    const float* d_I = (const float*)d_in[0];   // input_current (scalar)
    float* out = (float*)d_out;                 // T fp32 spikes

    const int nblocks = 512;
    int span = (out_size + nblocks - 1) / nblocks;
    span = (span + 3) & ~3;                     // x4-aligned spans
    lif_fused_kernel<<<nblocks, 256, 0, stream>>>(d_I, out, out_size, span);
}

// Round 4
// 11.270 us; speedup vs baseline: 1.9072x; 1.6778x over previous
//
#include <hip/hip_runtime.h>
#include <math.h>

// LIF neuron Euler integration, T = 3.5M steps, scalar input current.
//
// Structural insight (verified R1-R3, absmax = 0): every spike resets v to
// exactly V_RESET = 0.0f == initial state, so the fp32 dynamics are exactly
// periodic: spikes[t] = (t > 0 && t % P == 0), P = fp32 Euler steps from v=0
// to first v_new >= 1.0f (P = 220 for I = 1.5).
//
// R4 change: closed-form P instead of the 220-step serial loop on the
// critical path. Exact real dynamics: v_n = I*(1 - beta^n), beta = 1 -
// (double)alpha_f32 -> P = ceil(ln(1-1/I)/ln(beta)). Computed in fp64 with a
// safety-margin check: accept only if v(P-1) and v(P) are each > 2e-4 away
// from threshold (worst-case fp32 iteration drift is ~2.4e-5; I=1.5 margins
// are 4.1e-4 / 2.1e-3). Ambiguous or out-of-band inputs fall back to the
// bit-exact serial loop (contract off, reference op order). P is then ready
// in ~100ns, so ALL 256 threads write final values directly (mod-counter,
// one integer div per thread) -- no barrier-then-patch pass, no idle wave.
// Critical path = pure write-bound fill (~14 MB / 6.9 TB/s ~= 2 us).

__device__ __forceinline__ unsigned lif_period_exact(float I, int n_steps) {
#pragma clang fp contract(off)
    const float alpha = (float)(1e-4 / 0.02);  // == jnp.float32(DT / TAU)
    unsigned P = 0;
    float v = 0.0f;
    for (int t = 1; t < n_steps; ++t) {
        float v_new = v + (I - v) * alpha;     // == v + (-v + I)*alpha in IEEE
        if (v_new >= 1.0f) { P = (unsigned)t; break; }
        if (v_new == v) break;                 // converged below threshold
        v = v_new;
    }
    return P;
}

__global__ void lif_kernel(const float* __restrict__ input_current,
                           float* __restrict__ out, int n, int span) {
    __shared__ unsigned sP;

    const unsigned un = (unsigned)n;
    const unsigned lo = (unsigned)blockIdx.x * (unsigned)span;
    if (lo >= un) return;
    unsigned hi = lo + (unsigned)span;
    if (hi > un) hi = un;

    if (threadIdx.x == 0) {
        const float  I       = input_current[0];
        const float  alpha_f = (float)(1e-4 / 0.02);
        const double beta    = 1.0 - (double)alpha_f;
        const double dI      = (double)I;
        unsigned P = 0;
        bool resolved = false;

        if (dI >= 1.0 + 1e-3) {
            // closed form with margin verification
            double x  = 1.0 - 1.0 / dI;                 // in (0,1)
            double nn = log(x) / log(beta);             // real crossing point
            long   ng = (long)ceil(nn - 1e-9);
            long   nf = -1;
            for (long m = (ng > 3 ? ng - 2 : 1); m <= ng + 2; ++m) {
                double vm = dI * (1.0 - pow(beta, (double)m));
                if (vm >= 1.0) { nf = m; break; }
            }
            if (nf > 0) {
                double v_prev = dI * (1.0 - pow(beta, (double)(nf - 1)));
                double v_at   = dI * (1.0 - pow(beta, (double)nf));
                if ((1.0 - v_prev) > 2e-4 && (v_at - 1.0) > 2e-4) {
                    P = (unsigned)nf;
                    resolved = true;
                }
            }
        } else if (dI < 1.0 - 1e-3) {
            P = 0;            // fixed point v -> I well below threshold
            resolved = true;
        }
        if (!resolved) P = lif_period_exact(I, n);  // bit-exact fallback
        sP = P;
    }
    __syncthreads();

    const unsigned P = sP;
    unsigned i0 = lo + threadIdx.x * 4u;
    const unsigned step = 256u * 4u;

    if (P == 0u) {
        const float4 z = make_float4(0.f, 0.f, 0.f, 0.f);
        for (; i0 + 4u <= hi; i0 += step)
            *reinterpret_cast<float4*>(out + i0) = z;
        for (unsigned i = i0; i < hi && i < i0 + 4u; ++i) out[i] = 0.0f;
        return;
    }

    unsigned r    = i0 % P;     // one integer division per thread
    unsigned smod = step % P;   // uniform; add-with-wrap thereafter
    for (; i0 + 4u <= hi; i0 += step) {
        float4 vals;
        unsigned rr = r;
        vals.x = (rr == 0u && i0 != 0u) ? 1.0f : 0.0f;
        rr = (rr + 1u == P) ? 0u : rr + 1u;
        vals.y = (rr == 0u) ? 1.0f : 0.0f;
        rr = (rr + 1u == P) ? 0u : rr + 1u;
        vals.z = (rr == 0u) ? 1.0f : 0.0f;
        rr = (rr + 1u == P) ? 0u : rr + 1u;
        vals.w = (rr == 0u) ? 1.0f : 0.0f;
        *reinterpret_cast<float4*>(out + i0) = vals;
        r += smod;
        if (r >= P) r -= P;
    }
    // partial tail chunk (last block only, n % 4 != 0)
    if (i0 < hi) {
        unsigned rr = r;
        for (unsigned i = i0; i < hi && i < i0 + 4u; ++i) {
            out[i] = (rr == 0u && i != 0u) ? 1.0f : 0.0f;
            rr = (rr + 1u == P) ? 0u : rr + 1u;
        }
    }
}

extern "C" void kernel_launch(void* const* d_in, const int* in_sizes, int n_in,
                              void* d_out, int out_size, void* d_ws, size_t ws_size,
                              hipStream_t stream) {
    const float* d_I = (const float*)d_in[0];   // input_current (scalar)
    float* out = (float*)d_out;                 // T fp32 spikes

    const int nblocks = 1024;
    int span = (out_size + nblocks - 1) / nblocks;
    span = (span + 3) & ~3;                     // x4-aligned spans
    lif_kernel<<<nblocks, 256, 0, stream>>>(d_I, out, out_size, span);
}

// Round 5
// 10.711 us; speedup vs baseline: 2.0067x; 1.0522x over previous
//
#include <hip/hip_runtime.h>
#include <math.h>

// LIF neuron Euler integration, T = 3.5M steps, scalar input current.
//
// Structural insight (verified R1-R4, absmax = 0): every spike resets v to
// exactly V_RESET = 0.0f == initial state, so the fp32 dynamics are exactly
// periodic: spikes[t] = (t > 0 && t % P == 0), P = fp32 Euler steps from v=0
// to first v_new >= 1.0f (P = 220 for I = 1.5).
//
// R5 change: kill the fp64-libm prologue. R4 ran log()x2 + pow()x~7 (fp64
// SOFTWARE routines, ~2-3 us serially on one lane) on thread 0 of EVERY
// block while 255 threads waited at the barrier. Replace with:
//   seed:    n0 = log2f(x)/log2f(beta)  -- fp32 HW transcendentals (~60 cyc),
//            only needs +-1 accuracy (actual error ~5e-5 steps)
//   margins: beta^m by fp64 repeated squaring (HW mults only, ~30 deps),
//            v(m) = I*(1-beta^m) accurate to ~1e-14
//   accept candidate P only if both-side margins > 1e-4 + 4e-7*P (worst-case
//   accumulated fp32 iteration drift bound); else bit-exact serial fallback
//   (contract off, reference op order) -- never triggers for I = 1.5.
// Prologue drops to ~0.2 us; critical path = pure write-bound fill.

__device__ __forceinline__ unsigned lif_period_serial(float I, int n_steps) {
#pragma clang fp contract(off)
    const float alpha = (float)(1e-4 / 0.02);  // == jnp.float32(DT / TAU)
    unsigned P = 0;
    float v = 0.0f;
    for (int t = 1; t < n_steps; ++t) {
        float v_new = v + (I - v) * alpha;     // == v + (-v + I)*alpha in IEEE
        if (v_new >= 1.0f) { P = (unsigned)t; break; }
        if (v_new == v) break;                 // converged below threshold
        v = v_new;
    }
    return P;
}

__device__ __forceinline__ double pow_u(double b, unsigned e) {
    double r = 1.0, p = b;
    while (e) { if (e & 1u) r *= p; p *= p; e >>= 1; }
    return r;
}

__global__ void lif_kernel(const float* __restrict__ input_current,
                           float* __restrict__ out, int n, int span) {
    __shared__ unsigned sP;

    const unsigned un = (unsigned)n;
    const unsigned lo = (unsigned)blockIdx.x * (unsigned)span;
    if (lo >= un) return;
    unsigned hi = lo + (unsigned)span;
    if (hi > un) hi = un;

    if (threadIdx.x == 0) {
        const float I       = input_current[0];
        const float alpha_f = (float)(1e-4 / 0.02);
        unsigned P = 0;
        bool resolved = false;

        if (I >= 1.001f) {
            // fp32 HW-transcendental seed for the crossing index
            const float x    = 1.0f - 1.0f / I;           // >= ~1e-3
            const float l2x  = log2f(x);                  // < 0
            const float l2b  = log2f(1.0f - alpha_f);     // ~ -0.007232
            const float nn   = l2x / l2b;                 // real crossing ~219.17
            long m0 = (long)nn - 2;
            if (m0 < 1) m0 = 1;

            // exact margins via fp64 HW mults only (no libm)
            const double beta = 1.0 - (double)alpha_f;
            const double dI   = (double)I;
            double bm    = pow_u(beta, (unsigned)(m0 - 1));
            double vprev = dI * (1.0 - bm);
            long   found = -1;
            double vfound = 0.0, vbefore = 0.0;
            for (long m = m0; m <= m0 + 6; ++m) {
                bm *= beta;
                double vm = dI * (1.0 - bm);
                if (vm >= 1.0) { found = m; vfound = vm; vbefore = vprev; break; }
                vprev = vm;
            }
            if (found > 0) {
                // drift-adaptive margin: fp32 trajectory stays within
                // ~4e-7*m of the real one; demand clearance on both sides
                const double margin = 1e-4 + 4e-7 * (double)found;
                if ((1.0 - vbefore) > margin && (vfound - 1.0) > margin) {
                    P = (unsigned)found;
                    resolved = true;
                }
            }
        } else if (I < 0.999f) {
            P = 0;                       // fixed point v -> I, never crosses
            resolved = true;
        }
        if (!resolved) P = lif_period_serial(I, n);  // bit-exact fallback
        sP = P;
    }
    __syncthreads();

    const unsigned P = sP;
    unsigned i0 = lo + threadIdx.x * 4u;
    const unsigned step = 256u * 4u;

    if (P == 0u) {
        const float4 z = make_float4(0.f, 0.f, 0.f, 0.f);
        for (; i0 + 4u <= hi; i0 += step)
            *reinterpret_cast<float4*>(out + i0) = z;
        for (unsigned i = i0; i < hi && i < i0 + 4u; ++i) out[i] = 0.0f;
        return;
    }

    unsigned r    = i0 % P;     // one integer division per thread
    unsigned smod = step % P;   // uniform; add-with-wrap thereafter
    for (; i0 + 4u <= hi; i0 += step) {
        float4 vals;
        unsigned rr = r;
        vals.x = (rr == 0u && i0 != 0u) ? 1.0f : 0.0f;
        rr = (rr + 1u == P) ? 0u : rr + 1u;
        vals.y = (rr == 0u) ? 1.0f : 0.0f;
        rr = (rr + 1u == P) ? 0u : rr + 1u;
        vals.z = (rr == 0u) ? 1.0f : 0.0f;
        rr = (rr + 1u == P) ? 0u : rr + 1u;
        vals.w = (rr == 0u) ? 1.0f : 0.0f;
        *reinterpret_cast<float4*>(out + i0) = vals;
        r += smod;
        if (r >= P) r -= P;
    }
    // partial tail chunk (last block only, n % 4 != 0)
    if (i0 < hi) {
        unsigned rr = r;
        for (unsigned i = i0; i < hi && i < i0 + 4u; ++i) {
            out[i] = (rr == 0u && i != 0u) ? 1.0f : 0.0f;
            rr = (rr + 1u == P) ? 0u : rr + 1u;
        }
    }
}

extern "C" void kernel_launch(void* const* d_in, const int* in_sizes, int n_in,
                              void* d_out, int out_size, void* d_ws, size_t ws_size,
                              hipStream_t stream) {
    const float* d_I = (const float*)d_in[0];   // input_current (scalar)
    float* out = (float*)d_out;                 // T fp32 spikes

    const int nblocks = 1024;
    int span = (out_size + nblocks - 1) / nblocks;
    span = (span + 3) & ~3;                     // x4-aligned spans
    lif_kernel<<<nblocks, 256, 0, stream>>>(d_I, out, out_size, span);
}